// Round 22
// baseline (52.563 us; speedup 1.0000x reference)
//
#include <hip/hip_runtime.h>
#include <hip/hip_bf16.h>

typedef unsigned long long u64;
typedef unsigned int u32;

#define NB 64
#define NP 2048
#define NT 256
#define TK 8          // sorted top-K kept per row
#define RB 8          // rows resolved per greedy batch (RB*TK = 64 lanes)
#define EPSF 1e-7f

__device__ inline float iou1(const float4 pb, const float ap,
                             const float4 tb, const float at_eps) {
    float ix1 = fmaxf(pb.x, tb.x);
    float iy1 = fmaxf(pb.y, tb.y);
    float ix2 = fminf(pb.z, tb.z);
    float iy2 = fminf(pb.w, tb.w);
    float dx = fmaxf(ix2 - ix1, 0.f);
    float dy = fmaxf(iy2 - iy1, 0.f);
    float inter = dx * dy;
    float uni = (ap + at_eps) - inter;
    return inter * __builtin_amdgcn_rcpf(uni);
}

__device__ inline u64 wave_min_u64(u64 k) {
#pragma unroll
    for (int off = 1; off < 64; off <<= 1) {
        u32 lo = (u32)__shfl_xor((int)(u32)k, off);
        u32 hi = (u32)__shfl_xor((int)(u32)(k >> 32), off);
        u64 o = ((u64)hi << 32) | lo;
        if (o < k) k = o;
    }
    return k;  // uniform across lanes
}

// K1 (FUSED cost+topk): one block per target row. 1024 threads; thread owns
// preds {2tid, 2tid+1} for all 64 batches -> full row in-block, no cross-wave
// cost reduce. Then per-wave top-8 extraction (packed keys) + wave-0 merge of
// 128 candidates -> sorted top-8 + cost-row write. Pred array (2 MB) is
// L2-resident, so the per-row re-read streams from L2.
__global__ __launch_bounds__(1024) void row_kernel(const float4* __restrict__ pred,
                                                   const float* __restrict__ tgt,
                                                   float* __restrict__ cost,
                                                   u64* __restrict__ toplist) {
    __shared__ float4 sT4[NB];      // per-batch target box for row t
    __shared__ float sA[NB];        // area+eps
    __shared__ u64 sK[16 * TK];     // per-wave top-8 candidates
    const int tid = threadIdx.x;
    const int wv = tid >> 6, lane = tid & 63;
    const int t = blockIdx.x;

    if (tid < NB) {
        float4 tb = *(const float4*)&tgt[(tid * NT + t) * 4];
        sT4[tid] = tb;
        sA[tid] = (tb.z - tb.x) * (tb.w - tb.y) + EPSF;
    }
    __syncthreads();

    float acc0 = 0.f, acc1 = 0.f;
    for (int b = 0; b < NB; b += 4) {
        float4 ps[8];
#pragma unroll
        for (int u = 0; u < 4; ++u) {
            ps[2 * u]     = pred[(b + u) * NP + 2 * tid];
            ps[2 * u + 1] = pred[(b + u) * NP + 2 * tid + 1];
        }
#pragma unroll
        for (int u = 0; u < 4; ++u) {
            const float4 tb = sT4[b + u];
            const float at = sA[b + u];
            acc0 += iou1(ps[2 * u], (ps[2 * u].z - ps[2 * u].x) * (ps[2 * u].w - ps[2 * u].y), tb, at);
            acc1 += iou1(ps[2 * u + 1], (ps[2 * u + 1].z - ps[2 * u + 1].x) * (ps[2 * u + 1].w - ps[2 * u + 1].y), tb, at);
        }
    }
    const float c0 = 1.f - acc0 * (1.f / NB);
    const float c1 = 1.f - acc1 * (1.f / NB);
    *(float2*)&cost[(size_t)t * NP + 2 * tid] = make_float2(c0, c1);  // fallback reads this

    // per-wave sorted top-8 over its 128 values (packed key = valbits<<32|idx;
    // exactly reproduces argmin first-occurrence tie-break)
    const u64 kA = ((u64)__float_as_uint(c0) << 32) | (u32)(2 * tid);
    const u64 kB = ((u64)__float_as_uint(c1) << 32) | (u32)(2 * tid + 1);
    u32 used = 0;
    for (int e = 0; e < TK; ++e) {
        u64 a = (used & 1u) ? ~0ull : kA;
        u64 b = (used & 2u) ? ~0ull : kB;
        u64 best = a < b ? a : b;
        u32 bs = a < b ? 1u : 2u;
        u64 g = wave_min_u64(best);
        if (best == g) used |= bs;       // unique winner (idx in key)
        if (lane == 0) sK[wv * TK + e] = g;
    }
    __syncthreads();
    if (wv == 0) {                        // merge 128 candidates -> top-8
        u64 kM0 = sK[2 * lane], kM1 = sK[2 * lane + 1];
        u32 used2 = 0;
        for (int e = 0; e < TK; ++e) {
            u64 a = (used2 & 1u) ? ~0ull : kM0;
            u64 b = (used2 & 2u) ? ~0ull : kM1;
            u64 best = a < b ? a : b;
            u32 bs = a < b ? 1u : 2u;
            u64 g = wave_min_u64(best);
            if (best == g) used2 |= bs;
            if (lane == 0) toplist[t * TK + e] = g;
        }
    }
}

// cold path: exact masked argmin over the full cost row (first-occurrence).
__device__ __attribute__((noinline))
void fallback_pick(const float* __restrict__ row, u32 m, int lane,
                   u32* pickIdx, float* pickVal) {
    u64 best = ~0ull;
#pragma unroll 1
    for (int k = 0; k < 8; ++k) {
        float4 q = *(const float4*)(row + k * 256 + 4 * lane);
        float vv[4] = {q.x, q.y, q.z, q.w};
#pragma unroll
        for (int e = 0; e < 4; ++e) {
            u32 gidx = (u32)(k * 256 + 4 * lane + e);
            int w = __builtin_amdgcn_ds_bpermute((int)((gidx >> 5) << 2), (int)m);
            bool taken = (((u32)w >> (gidx & 31)) & 1u) != 0u;
            u32 hb = taken ? 0xFFFFFFFFu : __float_as_uint(vv[e]);
            u64 key = ((u64)hb << 32) | gidx;
            if (key < best) best = key;
        }
    }
    best = wave_min_u64(best);
    *pickIdx = (u32)best & (NP - 1);
    *pickVal = __uint_as_float((u32)(best >> 32));
}

// K3: byte-identical to R19 (best measured: optimistic parallel picks +
// single ballot, register preload + full unroll).
__global__ __launch_bounds__(64) void greedy_kernel(const u64* __restrict__ toplist,
                                                    const float* __restrict__ cost,
                                                    float* __restrict__ out) {
    const int lane = threadIdx.x;
    u32 idxr[32], vbr[32];
#pragma unroll
    for (int k = 0; k < 32; ++k) {
        u64 v = toplist[64 * k + lane];
        idxr[k] = (u32)v & (NP - 1);
        vbr[k] = (u32)(v >> 32);
    }

    u32 m = 0;
    float sum = 0.f;
    u64 A = ~0ull;

#pragma unroll
    for (int k = 0; k < 32; ++k) {
        const u32 idx = idxr[k];
        const u32 vb = vbr[k];
        int wn = 0;
        u32 idn = 0;
        if (k < 31) {
            idn = idxr[k + 1];
            wn = __builtin_amdgcn_ds_bpermute((int)((idn >> 5) << 2), (int)m);
        }

        u32 pidx[RB]; float pval[RB];

        bool empty = false;
        int f[RB];
#pragma unroll
        for (int g = 0; g < RB; ++g) {
            u64 bal = A & (0xFFull << (8 * g));
            empty = empty || (bal == 0);
            f[g] = (int)__ffsll(bal) - 1;
        }
        bool ok = !empty;
        if (ok) {
#pragma unroll
            for (int g = 0; g < RB; ++g) {
                pidx[g] = (u32)__builtin_amdgcn_readlane((int)idx, f[g]);
                pval[g] = __uint_as_float((u32)__builtin_amdgcn_readlane((int)vb, f[g]));
            }
            u32 confl = 0;
#pragma unroll
            for (int g = 1; g < RB; ++g)
#pragma unroll
                for (int h = 0; h < g; ++h)
                    confl |= (pidx[g] == pidx[h]) ? 1u : 0u;
            ok = (confl == 0);
        }

        if (ok) {   // fast path: one ballot per batch
#pragma unroll
            for (int g = 0; g < RB; ++g) {
                sum += pval[g];
                if ((pidx[g] >> 5) == (u32)lane) m |= (1u << (pidx[g] & 31));
            }
            if (k < 31) {
                bool availn = (((u32)wn >> (idn & 31)) & 1u) == 0u;
                bool hit = false;
#pragma unroll
                for (int g = 0; g < RB; ++g)
                    hit = hit || (idn == pidx[g]);
                A = __ballot(availn && !hit);
            }
        } else {    // exact serial redo (rare)
            u64 As = A;
#pragma unroll
            for (int gg = 0; gg < RB; ++gg) {
                u64 bal = As & (0xFFull << (8 * gg));
                u32 pi; float pv;
                if (bal != 0) {
                    int fs = (int)__ffsll(bal) - 1;
                    pi = (u32)__builtin_amdgcn_readlane((int)idx, fs);
                    pv = __uint_as_float((u32)__builtin_amdgcn_readlane((int)vb, fs));
                } else {
                    fallback_pick(cost + (size_t)(k * RB + gg) * NP, m, lane,
                                  &pi, &pv);
                }
                pidx[gg] = pi;
                pval[gg] = pv;
                sum += pv;
                if ((pi >> 5) == (u32)lane) m |= (1u << (pi & 31));
                As &= ~__ballot(idx == pi);
            }
            if (k < 31) {
                u64 An = __ballot((((u32)wn >> (idn & 31)) & 1u) == 0u);
#pragma unroll
                for (int g = 0; g < RB; ++g)
                    An &= ~__ballot(idn == pidx[g]);
                A = An;
            }
        }
    }
    if (lane == 0) out[0] = sum * (1.f / NT);
}

extern "C" void kernel_launch(void* const* d_in, const int* in_sizes, int n_in,
                              void* d_out, int out_size, void* d_ws, size_t ws_size,
                              hipStream_t stream) {
    const float4* pred = (const float4*)d_in[0];
    const float* tgt = (const float*)d_in[1];
    char* ws = (char*)d_ws;
    float* cost  = (float*)ws;                           // 2 MB
    u64* toplist = (u64*)(ws + (size_t)NT * NP * 4);     // 16 KB

    row_kernel<<<NT, 1024, 0, stream>>>(pred, tgt, cost, toplist);
    greedy_kernel<<<1, 64, 0, stream>>>(toplist, cost, (float*)d_out);
}

// Round 23
// 46.436 us; speedup vs baseline: 1.1319x; 1.1319x over previous
//
#include <hip/hip_runtime.h>
#include <hip/hip_bf16.h>

typedef unsigned long long u64;
typedef unsigned int u32;

#define NB 64
#define NP 2048
#define NT 256
#define TK 8          // sorted top-K kept per row
#define RB 8          // rows resolved per greedy batch (RB*TK = 64 lanes)
#define TT 8          // targets per cost block
#define PB 128        // preds per cost block (2 per lane)
#define EPSF 1e-7f

__device__ inline float iou1(const float4 pb, const float ap,
                             const float4 tb, const float at_eps) {
    float ix1 = fmaxf(pb.x, tb.x);
    float iy1 = fmaxf(pb.y, tb.y);
    float ix2 = fminf(pb.z, tb.z);
    float iy2 = fminf(pb.w, tb.w);
    float dx = fmaxf(ix2 - ix1, 0.f);
    float dy = fmaxf(iy2 - iy1, 0.f);
    float inter = dx * dy;
    float uni = (ap + at_eps) - inter;
    return inter * __builtin_amdgcn_rcpf(uni);
}

// K1: best-measured cost kernel (R15 config, ~14us warm).
__global__ __launch_bounds__(512, 4) void cost_kernel(const float4* __restrict__ pred,
                                                      const float* __restrict__ tgt,
                                                      float* __restrict__ cost) {
    __shared__ float4 sT[NB * TT];        // [b][tt] coords (8 KB)
    __shared__ float sRed[8][TT][PB];     // per-wave partials (32 KB)
    const int tid = threadIdx.x;
    const int wv = tid >> 6, lane = tid & 63;
    const int p0 = blockIdx.x * PB + lane;      // second pred = p0 + 64
    const int t0 = blockIdx.y * TT;

    {
        int b = tid >> 3, tt = tid & 7;
        sT[tid] = *(const float4*)&tgt[(b * NT + t0 + tt) * 4];
    }
    __syncthreads();

    float acc0[TT] = {0.f, 0.f, 0.f, 0.f, 0.f, 0.f, 0.f, 0.f};
    float acc1[TT] = {0.f, 0.f, 0.f, 0.f, 0.f, 0.f, 0.f, 0.f};

    const int b0 = wv * 8;
#pragma unroll
    for (int i = 0; i < 8; ++i) {
        const int b = b0 + i;
        const float4 pa = pred[b * NP + p0];
        const float4 pc = pred[b * NP + p0 + 64];
        const float apa = (pa.z - pa.x) * (pa.w - pa.y);
        const float apc = (pc.z - pc.x) * (pc.w - pc.y);
#pragma unroll
        for (int tt = 0; tt < TT; ++tt) {
            const float4 tb = sT[b * TT + tt];
            const float at = (tb.z - tb.x) * (tb.w - tb.y) + EPSF;
            acc0[tt] += iou1(pa, apa, tb, at);
            acc1[tt] += iou1(pc, apc, tb, at);
        }
    }
#pragma unroll
    for (int tt = 0; tt < TT; ++tt) {
        sRed[wv][tt][lane] = acc0[tt];
        sRed[wv][tt][lane + 64] = acc1[tt];
    }
    __syncthreads();

    if (tid < 256) {
        const int tt = tid >> 5, q = tid & 31;
        float4 s = {0.f, 0.f, 0.f, 0.f};
#pragma unroll
        for (int w = 0; w < 8; ++w) {
            float4 a = *(const float4*)&sRed[w][tt][q * 4];
            s.x += a.x; s.y += a.y; s.z += a.z; s.w += a.w;
        }
        float4 c;
        c.x = 1.f - s.x * (1.f / NB);
        c.y = 1.f - s.y * (1.f / NB);
        c.z = 1.f - s.z * (1.f / NB);
        c.w = 1.f - s.w * (1.f / NB);
        *(float4*)&cost[(size_t)(t0 + tt) * NP + blockIdx.x * PB + q * 4] = c;
    }
}

__device__ inline u64 wave_min_u64(u64 k) {
#pragma unroll
    for (int off = 1; off < 64; off <<= 1) {
        u32 lo = (u32)__shfl_xor((int)(u32)k, off);
        u32 hi = (u32)__shfl_xor((int)(u32)(k >> 32), off);
        u64 o = ((u64)hi << 32) | lo;
        if (o < k) k = o;
    }
    return k;  // uniform across lanes
}

// K2: 4 waves/row; per-wave sorted top-8 on packed (valbits<<32|idx) keys
// (exactly reproduces argmin first-occurrence tie-break), wave-0 merge.
__global__ __launch_bounds__(256) void topk_kernel(const float* __restrict__ cost,
                                                   u64* __restrict__ toplist) {
    __shared__ u64 sK[32];
    const int tid = threadIdx.x;
    const int wv = tid >> 6, lane = tid & 63;
    const int t = blockIdx.x;
    const float* row = cost + (size_t)t * NP;

    float v[8];
#pragma unroll
    for (int c = 0; c < 2; ++c) {
        float4 q = *(const float4*)(row + wv * 512 + c * 256 + 4 * lane);
        v[4 * c + 0] = q.x; v[4 * c + 1] = q.y;
        v[4 * c + 2] = q.z; v[4 * c + 3] = q.w;
    }
    u32 used = 0;
    for (int e = 0; e < TK; ++e) {
        u64 best = ~0ull;
        u32 bs = 0;
#pragma unroll
        for (int s = 0; s < 8; ++s) {
            u32 hb = ((used >> s) & 1u) ? 0xFFFFFFFFu : __float_as_uint(v[s]);
            u32 gidx = (u32)(wv * 512 + (s >> 2) * 256 + 4 * lane + (s & 3));
            u64 key = ((u64)hb << 32) | gidx;
            if (key < best) { best = key; bs = (u32)s; }
        }
        u64 g = wave_min_u64(best);
        if (best == g) used |= (1u << bs);   // unique winner (idx in key)
        if (lane == 0) sK[wv * TK + e] = g;
    }
    __syncthreads();
    if (wv == 0) {
        u64 k = (lane < 32) ? sK[lane] : ~0ull;
        for (int e = 0; e < TK; ++e) {
            u64 g = wave_min_u64(k);
            if (k == g) k = ~0ull;           // clear unique winner
            if (lane == 0) toplist[t * TK + e] = g;
        }
    }
}

// cold path: exact masked argmin over the full cost row (first-occurrence)
__device__ void fallback_pick(const float* __restrict__ row, u32 m, int lane,
                              u32* pickIdx, float* pickVal) {
    u64 best = ~0ull;
#pragma unroll 1
    for (int k = 0; k < 8; ++k) {
        float4 q = *(const float4*)(row + k * 256 + 4 * lane);
        float vv[4] = {q.x, q.y, q.z, q.w};
#pragma unroll
        for (int e = 0; e < 4; ++e) {
            u32 gidx = (u32)(k * 256 + 4 * lane + e);
            int w = __builtin_amdgcn_ds_bpermute((int)((gidx >> 5) << 2), (int)m);
            bool taken = (((u32)w >> (gidx & 31)) & 1u) != 0u;
            u32 hb = taken ? 0xFFFFFFFFu : __float_as_uint(vv[e]);
            u64 key = ((u64)hb << 32) | gidx;
            if (key < best) best = key;
        }
    }
    best = wave_min_u64(best);
    *pickIdx = (u32)best & (NP - 1);
    *pickVal = __uint_as_float((u32)(best >> 32));
}

// K3: best-measured greedy (R19): optimistic parallel picks + single ballot
// per batch, full register preload + unrolled k-loop.
__global__ __launch_bounds__(64) void greedy_kernel(const u64* __restrict__ toplist,
                                                    const float* __restrict__ cost,
                                                    float* __restrict__ out) {
    const int lane = threadIdx.x;
    u32 idxr[32], vbr[32];
#pragma unroll
    for (int k = 0; k < 32; ++k) {
        u64 v = toplist[64 * k + lane];
        idxr[k] = (u32)v & (NP - 1);
        vbr[k] = (u32)(v >> 32);
    }

    u32 m = 0;
    float sum = 0.f;
    u64 A = ~0ull;

#pragma unroll
    for (int k = 0; k < 32; ++k) {
        const u32 idx = idxr[k];
        const u32 vb = vbr[k];
        int wn = 0;
        u32 idn = 0;
        if (k < 31) {
            idn = idxr[k + 1];
            wn = __builtin_amdgcn_ds_bpermute((int)((idn >> 5) << 2), (int)m);
        }

        u32 pidx[RB]; float pval[RB];

        // ---- optimistic parallel resolution ----
        bool empty = false;
        int f[RB];
#pragma unroll
        for (int g = 0; g < RB; ++g) {
            u64 bal = A & (0xFFull << (8 * g));
            empty = empty || (bal == 0);
            f[g] = (int)__ffsll(bal) - 1;
        }
        bool ok = !empty;
        if (ok) {
#pragma unroll
            for (int g = 0; g < RB; ++g) {
                pidx[g] = (u32)__builtin_amdgcn_readlane((int)idx, f[g]);
                pval[g] = __uint_as_float((u32)__builtin_amdgcn_readlane((int)vb, f[g]));
            }
            u32 confl = 0;
#pragma unroll
            for (int g = 1; g < RB; ++g)
#pragma unroll
                for (int h = 0; h < g; ++h)
                    confl |= (pidx[g] == pidx[h]) ? 1u : 0u;
            ok = (confl == 0);
        }

        if (ok) {   // fast path: one ballot per batch
#pragma unroll
            for (int g = 0; g < RB; ++g) {
                sum += pval[g];
                if ((pidx[g] >> 5) == (u32)lane) m |= (1u << (pidx[g] & 31));
            }
            if (k < 31) {
                bool availn = (((u32)wn >> (idn & 31)) & 1u) == 0u;
                bool hit = false;
#pragma unroll
                for (int g = 0; g < RB; ++g)
                    hit = hit || (idn == pidx[g]);
                A = __ballot(availn && !hit);        // the ONE ballot
            }
        } else {    // exact serial redo (rare: conflict or empty byte)
            u64 As = A;
#pragma unroll
            for (int gg = 0; gg < RB; ++gg) {
                u64 bal = As & (0xFFull << (8 * gg));
                if (bal != 0) {
                    int fs = (int)__ffsll(bal) - 1;
                    pidx[gg] = (u32)__builtin_amdgcn_readlane((int)idx, fs);
                    pval[gg] = __uint_as_float((u32)__builtin_amdgcn_readlane((int)vb, fs));
                } else {
                    fallback_pick(cost + (size_t)(k * RB + gg) * NP, m, lane,
                                  &pidx[gg], &pval[gg]);
                }
                sum += pval[gg];
                if ((pidx[gg] >> 5) == (u32)lane) m |= (1u << (pidx[gg] & 31));
                As &= ~__ballot(idx == pidx[gg]);
            }
            if (k < 31) {
                u64 An = __ballot((((u32)wn >> (idn & 31)) & 1u) == 0u);
#pragma unroll
                for (int g = 0; g < RB; ++g)
                    An &= ~__ballot(idn == pidx[g]);
                A = An;
            }
        }
    }
    if (lane == 0) out[0] = sum * (1.f / NT);
}

extern "C" void kernel_launch(void* const* d_in, const int* in_sizes, int n_in,
                              void* d_out, int out_size, void* d_ws, size_t ws_size,
                              hipStream_t stream) {
    const float4* pred = (const float4*)d_in[0];
    const float* tgt = (const float*)d_in[1];
    char* ws = (char*)d_ws;
    float* cost  = (float*)ws;                           // 2 MB
    u64* toplist = (u64*)(ws + (size_t)NT * NP * 4);     // 16 KB

    cost_kernel<<<dim3(NP / PB, NT / TT), 512, 0, stream>>>(pred, tgt, cost);
    topk_kernel<<<NT, 256, 0, stream>>>(cost, toplist);
    greedy_kernel<<<1, 64, 0, stream>>>(toplist, cost, (float*)d_out);
}